// Round 5
// baseline (578.088 us; speedup 1.0000x reference)
//
#include <hip/hip_runtime.h>
#include <math.h>

// (B, CIN, CGD, CE, G, H, W) = (4, 256, 256, 64, 4, 80, 80)
#define NB    4
#define CINC  256
#define NG    4
#define NPIX  6400
#define NROWS 132           // gemm rows: 64 embed + 64 guide + 4 conf
#define EMBW  128           // stored emb row width (embed+guide only)
#define XW    260           // xspo row: 4 groups x (64 ch + norm)
#define TEPS  1e-8f
#define TP    128
#define KC    32
#define SCH   5             // sweep channels per block (13 chunks x 5 = 65)
#define TPITCH 65           // LDS tile pitch (65%32==1 -> conflict-free columns)

typedef unsigned short u16;
typedef unsigned int   u32;

// ---------------------------------------------------------------------------
// prep: levels (pointer doubling), level starts, u16 parent, u16 inverse
// order, u16 child-range starts (parent[] monotone => contiguous children;
// cstart[u] = lower_bound(par, u), children(u) = [cstart[u], cstart[u+1])).
// ---------------------------------------------------------------------------
__global__ __launch_bounds__(256) void prep_kernel(
    const int* __restrict__ order, const int* __restrict__ parent,
    u16* __restrict__ par16, u16* __restrict__ cst16, int* __restrict__ ls,
    int* __restrict__ nl, u16* __restrict__ inv16)
{
  const int b = blockIdx.x;
  const int tid = threadIdx.x;
  const int* par = parent + b*NPIX;
  const int* ord = order + b*NPIX;
  __shared__ int lvl[NPIX];
  __shared__ int anc[NPIX];
  __shared__ int smax;

  #pragma unroll
  for (int it = 0; it < NPIX/256; ++it) {
    int k = tid + it*256;
    int p = par[k];
    lvl[k] = (k == 0) ? 0 : 1;
    anc[k] = p;
    inv16[b*NPIX + ord[k]] = (u16)k;
    par16[b*NPIX + k] = (u16)p;
  }
  __syncthreads();

  for (int r = 0; r < 13; ++r) {          // 2^13 = 8192 > 6400
    int nlv[NPIX/256], nan_[NPIX/256];
    #pragma unroll
    for (int it = 0; it < NPIX/256; ++it) {
      int k = tid + it*256;
      int a = anc[k];
      nlv[it]  = lvl[k] + lvl[a];
      nan_[it] = anc[a];
    }
    __syncthreads();
    #pragma unroll
    for (int it = 0; it < NPIX/256; ++it) {
      int k = tid + it*256;
      lvl[k] = nlv[it];
      anc[k] = nan_[it];
    }
    __syncthreads();
  }

  if (tid == 0) smax = 0;
  __syncthreads();
  int m = 0;
  #pragma unroll
  for (int it = 0; it < NPIX/256; ++it) m = max(m, lvl[tid + it*256]);
  atomicMax(&smax, m);
  __syncthreads();
  if (tid == 0) {
    nl[b] = smax + 1;
    ls[b*(NPIX+2) + smax + 1] = NPIX;
  }
  #pragma unroll
  for (int it = 0; it < NPIX/256; ++it) {
    int k = tid + it*256;
    if (k == 0 || lvl[k] != lvl[k-1]) ls[b*(NPIX+2) + lvl[k]] = k;
  }

  // reuse anc[] as LDS copy of par for binary search
  __syncthreads();
  #pragma unroll
  for (int it = 0; it < NPIX/256; ++it) { int k = tid + it*256; anc[k] = par[k]; }
  __syncthreads();
  for (int u = tid; u <= NPIX; u += 256) {
    int lo = 1, hi = NPIX;
    while (lo < hi) { int mid = (lo+hi) >> 1; if (anc[mid] < u) lo = mid+1; else hi = mid; }
    cst16[b*6402 + u] = (u16)lo;
  }
}

// ---------------------------------------------------------------------------
// GEMM: emb[b][n][0..127] = [W_embed@f ; W_guide@g]; confA[b][g][n] = sigmoid.
// ---------------------------------------------------------------------------
__global__ __launch_bounds__(512) void gemm_kernel(
    const float* __restrict__ f, const float* __restrict__ g,
    const float* __restrict__ We, const float* __restrict__ Wc,
    const float* __restrict__ Wg, float* __restrict__ emb,
    float* __restrict__ confA)
{
  const int b  = blockIdx.y;
  const int t0 = blockIdx.x * TP;
  const int tid = threadIdx.x;
  const int i = tid >> 5;   // 0..15
  const int j = tid & 31;   // 0..31

  __shared__ float fT[KC][TP];
  __shared__ float gT[KC][TP];
  __shared__ float wT[NROWS][KC];

  float acc[9][4];
  #pragma unroll
  for (int a = 0; a < 9; ++a)
    #pragma unroll
    for (int p = 0; p < 4; ++p) acc[a][p] = 0.f;

  const float* fb = f + (size_t)b*CINC*NPIX;
  const float* gb = g + (size_t)b*CINC*NPIX;

  for (int kc = 0; kc < CINC; kc += KC) {
    {
      int idx = tid * 8;
      int kk = idx / TP, p = idx - kk*TP;
      const float4* srcf = reinterpret_cast<const float4*>(fb + (size_t)(kc+kk)*NPIX + t0 + p);
      const float4* srcg = reinterpret_cast<const float4*>(gb + (size_t)(kc+kk)*NPIX + t0 + p);
      float4 v0 = srcf[0], v1 = srcf[1];
      fT[kk][p+0]=v0.x; fT[kk][p+1]=v0.y; fT[kk][p+2]=v0.z; fT[kk][p+3]=v0.w;
      fT[kk][p+4]=v1.x; fT[kk][p+5]=v1.y; fT[kk][p+6]=v1.z; fT[kk][p+7]=v1.w;
      v0 = srcg[0]; v1 = srcg[1];
      gT[kk][p+0]=v0.x; gT[kk][p+1]=v0.y; gT[kk][p+2]=v0.z; gT[kk][p+3]=v0.w;
      gT[kk][p+4]=v1.x; gT[kk][p+5]=v1.y; gT[kk][p+6]=v1.z; gT[kk][p+7]=v1.w;
    }
    for (int s = tid; s < 528; s += 512) {
      int idx = s * 8;
      int r = idx / KC, kb = idx - r*KC;
      const float* wsrc;
      if (r < 64)       wsrc = We + r*CINC + kc + kb;
      else if (r < 128) wsrc = Wg + (r-64)*CINC + kc + kb;
      else              wsrc = Wc + (r-128)*CINC + kc + kb;
      const float4* wv = reinterpret_cast<const float4*>(wsrc);
      float4 v0 = wv[0], v1 = wv[1];
      wT[r][kb+0]=v0.x; wT[r][kb+1]=v0.y; wT[r][kb+2]=v0.z; wT[r][kb+3]=v0.w;
      wT[r][kb+4]=v1.x; wT[r][kb+5]=v1.y; wT[r][kb+6]=v1.z; wT[r][kb+7]=v1.w;
    }
    __syncthreads();

    #pragma unroll 4
    for (int kk = 0; kk < KC; ++kk) {
      float xf0 = fT[kk][j], xf1 = fT[kk][j+32], xf2 = fT[kk][j+64], xf3 = fT[kk][j+96];
      float xg0 = gT[kk][j], xg1 = gT[kk][j+32], xg2 = gT[kk][j+64], xg3 = gT[kk][j+96];
      #pragma unroll
      for (int rr = 0; rr < 4; ++rr) {
        float a = wT[i + 16*rr][kk];
        acc[rr][0] += a*xf0; acc[rr][1] += a*xf1; acc[rr][2] += a*xf2; acc[rr][3] += a*xf3;
      }
      #pragma unroll
      for (int rr = 4; rr < 8; ++rr) {
        float a = wT[i + 16*rr][kk];
        acc[rr][0] += a*xg0; acc[rr][1] += a*xg1; acc[rr][2] += a*xg2; acc[rr][3] += a*xg3;
      }
      if (i < 4) {
        float a = wT[128 + i][kk];
        acc[8][0] += a*xf0; acc[8][1] += a*xf1; acc[8][2] += a*xf2; acc[8][3] += a*xf3;
      }
    }
    __syncthreads();
  }

  float* eb = emb + (size_t)b*NPIX*EMBW;
  #pragma unroll
  for (int rr = 0; rr < 8; ++rr) {
    int r = i + 16*rr;
    #pragma unroll
    for (int p = 0; p < 4; ++p) {
      int n = t0 + j + 32*p;
      eb[(size_t)n*EMBW + r] = acc[rr][p];
    }
  }
  if (i < 4) {
    #pragma unroll
    for (int p = 0; p < 4; ++p) {
      int n = t0 + j + 32*p;
      confA[((size_t)b*NG + i)*NPIX + n] = 1.f / (1.f + expf(-acc[8][p]));
    }
  }
}

// ---------------------------------------------------------------------------
// Edge weights: wave-per-edge coalesced row reads + 16-lane shuffle reduce.
// wq[b][g][k] = round(65535 * exp(-(d_e+d_g+beta^2)))
// ---------------------------------------------------------------------------
__global__ __launch_bounds__(256) void wdist_kernel(
    const float* __restrict__ emb, const int* __restrict__ order,
    const int* __restrict__ parent, const float* __restrict__ beta,
    u16* __restrict__ wq)
{
  __shared__ int s_n[64], s_np[64];
  __shared__ u16 s_wt[NG][64];
  __shared__ float s_beta[NG];
  const int bid = blockIdx.x;           // b*100 + tile
  const int b = bid / 100;
  const int k0 = (bid - b*100)*64;
  const int tid = threadIdx.x;
  const int wv = tid >> 6, l = tid & 63;

  if (tid < 64) {
    int k = k0 + tid;
    s_n[tid]  = order[b*NPIX + k];
    s_np[tid] = order[b*NPIX + parent[b*NPIX + k]];
  }
  if (tid < NG) s_beta[tid] = beta[tid];
  __syncthreads();

  const float* eb = emb + (size_t)b*NPIX*EMBW;
  for (int i = 0; i < 16; ++i) {
    int e = wv*16 + i;
    const float* r0 = eb + (size_t)s_n[e]*EMBW;
    const float* r1 = eb + (size_t)s_np[e]*EMBW;
    float d0 = r0[l]    - r1[l];
    float d1 = r0[l+64] - r1[l+64];
    float d = d0*d0 + d1*d1;
    d += __shfl_xor(d, 1);
    d += __shfl_xor(d, 2);
    d += __shfl_xor(d, 4);
    d += __shfl_xor(d, 8);
    if ((l & 15) == 0) {
      int gg = l >> 4;
      float bg = s_beta[gg];
      float w = expf(-(d + bg*bg));
      s_wt[gg][e] = (u16)(w*65535.f + 0.5f);
    }
  }
  __syncthreads();
  if (tid < 128) {
    int gg = tid >> 5, j = tid & 31;
    u32* dst = (u32*)(wq + ((size_t)(b*NG+gg))*NPIX + k0);
    dst[j] = ((u32*)s_wt[gg])[j];
  }
}

// ---------------------------------------------------------------------------
// xbuild: x rows written directly in BFS order: xspo[b][k][g*65+c],
// c<64: f[g*64+c]*conf[g]; c==64: conf[g]. LDS-tiled, both sides coalesced.
// ---------------------------------------------------------------------------
__global__ __launch_bounds__(256) void xbuild_kernel(
    const float* __restrict__ f, const float* __restrict__ confA,
    const u16* __restrict__ inv16, float* __restrict__ xspo)
{
  extern __shared__ float tile[];       // [XW][TPITCH]
  __shared__ float s_cf[NG][64];
  __shared__ u16 s_k[64];
  const int bid = blockIdx.x;           // b*100 + tile
  const int b = bid / 100;
  const int n0 = (bid - b*100)*64;
  const int tid = threadIdx.x;
  const int wv = tid >> 6, l = tid & 63;

  s_cf[wv][l] = confA[((size_t)b*NG + wv)*NPIX + n0 + l];
  if (tid < 64) s_k[tid] = inv16[b*NPIX + n0 + tid];
  __syncthreads();

  {
    const float* fb = f + ((size_t)b*CINC)*NPIX + n0 + l;
    float cf = s_cf[wv][l];
    for (int cc = 0; cc < 64; ++cc) {
      int ch = wv*64 + cc;
      tile[(wv*65+cc)*TPITCH + l] = fb[(size_t)ch*NPIX] * cf;
    }
    tile[(wv*65+64)*TPITCH + l] = cf;
  }
  __syncthreads();

  for (int rr = 0; rr < 16; ++rr) {
    int row = wv*16 + rr;
    float* dst = xspo + ((size_t)b*NPIX + s_k[row])*XW;
    #pragma unroll
    for (int j = 0; j < 4; ++j) {
      int c = l + j*64;
      dst[c] = tile[c*TPITCH + row];
    }
    if (l < 4) { int c = 256 + l; dst[c] = tile[c*TPITCH + row]; }
  }
}

// ---------------------------------------------------------------------------
// Tree filter, LDS-resident, node-major (conflict-free). UP: 2-level windows
// (children + grandchildren gather, no atomics) with per-level fallback.
// DOWN: per-level, in place. In-place load/writeback on xspo slices.
// ---------------------------------------------------------------------------
__global__ __launch_bounds__(64, 1) void sweep_kernel(
    float* __restrict__ xspo, const u16* __restrict__ wq,
    const u16* __restrict__ par16, const u16* __restrict__ cst16,
    const int* __restrict__ ls, const int* __restrict__ nl)
{
  extern __shared__ char smem[];
  float* s_agg = (float*)smem;                  // 5*6400*4 = 128000 B
  u16*  s_w    = (u16*)(smem + 128000);         // 12800 B
  u16*  s_buf  = (u16*)(smem + 140800);         // 12804 B (cstart, then parent)
  u32*  s_w32  = (u32*)s_w;
  u32*  s_b32  = (u32*)s_buf;

  const int bid = blockIdx.x;
  const int b = bid / (NG*13);
  const int r = bid - b*(NG*13);
  const int g = r / 13;
  const int chunk = r - g*13;
  const int off = g*65 + chunk*SCH;
  const int tid = threadIdx.x;

  // ---- load: 20B slice per node from xspo; w; cstart ----
  {
    float* base = xspo + ((size_t)b*NPIX)*XW + off;
    for (int i = tid; i < NPIX; i += 64) {
      const float* src = base + (size_t)i*XW;
      float* dst = s_agg + i*SCH;
      dst[0]=src[0]; dst[1]=src[1]; dst[2]=src[2]; dst[3]=src[3]; dst[4]=src[4];
    }
    const u32* wsrc = (const u32*)(wq + (size_t)(b*NG+g)*NPIX);
    const u32* csrc = (const u32*)(cst16 + (size_t)b*6402);
    for (int i = tid; i < NPIX/2; i += 64) s_w32[i] = wsrc[i];
    for (int i = tid; i < 3201;   i += 64) s_b32[i] = csrc[i];
  }
  const int* lsb = ls + b*(NPIX+2);
  const int L = nl[b];
  __syncthreads();

  const float qs = 1.0f/65535.0f;

  // ---- UP ----
  {
    int lev = L-2;
    int c_m1 = lsb[lev+1];
    int c_0  = lsb[lev];
    int c_p1 = lsb[(lev-1>0)?lev-1:0];
    int c_p2 = lsb[(lev-2>0)?lev-2:0];
    int c_p3 = lsb[(lev-3>0)?lev-3:0];
    while (lev >= 0) {
      int i4 = (lev-4>0)?lev-4:0, i5 = (lev-5>0)?lev-5:0;
      int n4 = lsb[i4], n5 = lsb[i5];          // rolling prefetch
      int s1 = c_0, e1 = c_m1;
      bool fast = false;
      if (lev >= 1) {
        int s0 = c_p1;
        int items = (e1 - s0)*SCH;
        if (items <= 64) {
          fast = true;
          float a = 0.f; int node = 0, c = 0;
          const bool act = (tid < items);
          if (act) {
            node = s0 + tid/SCH; c = tid - (tid/SCH)*SCH;
            a = s_agg[node*SCH + c];
            int j0 = s_buf[node], j1 = s_buf[node+1];
            if (node >= s1) {
              // v-role (level lev): gather finalized children (lev+1)
              for (int j = j0; j < j1; ++j)
                a += (float)s_w[j]*qs * s_agg[j*SCH + c];
            } else {
              // u-role (level lev-1): children's pristine x + grandchildren
              for (int j = j0; j < j1; ++j) {
                float wj = (float)s_w[j]*qs;
                float sum = s_agg[j*SCH + c];
                int q0 = s_buf[j], q1 = s_buf[j+1];
                for (int q = q0; q < q1; ++q)
                  sum += (float)s_w[q]*qs * s_agg[q*SCH + c];
                a += wj * sum;
              }
            }
          }
          __syncthreads();     // fence: all loads before any store
          if (act) s_agg[node*SCH + c] = a;
          __syncthreads();
        }
      }
      if (!fast) {
        int items = (e1 - s1)*SCH;
        for (int t = tid; t < items; t += 64) {
          int node = s1 + t/SCH, c = t - (t/SCH)*SCH;
          float a = s_agg[node*SCH + c];
          int j0 = s_buf[node], j1 = s_buf[node+1];
          for (int j = j0; j < j1; ++j)
            a += (float)s_w[j]*qs * s_agg[j*SCH + c];
          s_agg[node*SCH + c] = a;
        }
        __syncthreads();
      }
      if (fast) { c_m1=c_p1; c_0=c_p2; c_p1=c_p3; c_p2=n4; c_p3=n5; lev -= 2; }
      else      { c_m1=c_0;  c_0=c_p1; c_p1=c_p2; c_p2=c_p3; c_p3=n4; lev -= 1; }
    }
  }

  // ---- reload buf with parent ----
  {
    const u32* psrc = (const u32*)(par16 + (size_t)b*NPIX);
    for (int i = tid; i < NPIX/2; i += 64) s_b32[i] = psrc[i];
  }
  __syncthreads();

  // ---- DOWN (in place): out[k] = a + w*(out[p] - w*a) ----
  {
    int lev = 1;
    int A = lsb[1], Bv = lsb[2];
    while (lev < L) {
      int ni = lev+2; if (ni > L) ni = L;
      int nx = lsb[ni];
      int items = (Bv - A)*SCH;
      for (int t = tid; t < items; t += 64) {
        int node = A + t/SCH, c = t - (t/SCH)*SCH;
        int p = s_buf[node];
        float wv = (float)s_w[node]*qs;
        float a  = s_agg[node*SCH + c];
        float op = s_agg[p*SCH + c];
        s_agg[node*SCH + c] = fmaf(wv, op - wv*a, a);
      }
      __syncthreads();
      A = Bv; Bv = nx; ++lev;
    }
  }

  // ---- writeback in place ----
  {
    float* base = xspo + ((size_t)b*NPIX)*XW + off;
    for (int i = tid; i < NPIX; i += 64) {
      float* dst = base + (size_t)i*XW;
      const float* src = s_agg + i*SCH;
      dst[0]=src[0]; dst[1]=src[1]; dst[2]=src[2]; dst[3]=src[3]; dst[4]=src[4];
    }
  }
}

// ---------------------------------------------------------------------------
// Epilogue: LDS-tiled gather of 64 node rows, normalize, residual, coalesced
// writes (wave-per-group).
// ---------------------------------------------------------------------------
__global__ __launch_bounds__(256) void epilogue_kernel(
    const float* __restrict__ xspo, const u16* __restrict__ inv16,
    const float* __restrict__ f, const float* __restrict__ gamma,
    float* __restrict__ out)
{
  extern __shared__ float tile[];       // [XW][TPITCH]
  __shared__ u16 s_k[64];
  const int bid = blockIdx.x;           // b*100 + tile
  const int b = bid / 100;
  const int n0 = (bid - b*100)*64;
  const int tid = threadIdx.x;
  const int wv = tid >> 6, l = tid & 63;

  if (tid < 64) s_k[tid] = inv16[b*NPIX + n0 + tid];
  __syncthreads();

  for (int rr = 0; rr < 16; ++rr) {
    int row = wv*16 + rr;
    const float* src = xspo + ((size_t)b*NPIX + s_k[row])*XW;
    #pragma unroll
    for (int j = 0; j < 4; ++j) {
      int c = l + j*64;
      tile[c*TPITCH + row] = src[c];
    }
    if (l < 4) { int c = 256 + l; tile[c*TPITCH + row] = src[c]; }
  }
  __syncthreads();

  float gam = gamma[0];
  float rn = 1.f / (TEPS + tile[(wv*65+64)*TPITCH + l]);
  const float* fb = f   + ((size_t)b*CINC)*NPIX + n0 + l;
  float* ob       = out + ((size_t)b*CINC)*NPIX + n0 + l;
  for (int cc = 0; cc < 64; ++cc) {
    int ch = wv*64 + cc;
    float res = tile[(wv*65+cc)*TPITCH + l] * rn;
    ob[(size_t)ch*NPIX] = fmaf(gam, res, fb[(size_t)ch*NPIX]);
  }
}

// ---------------------------------------------------------------------------
extern "C" void kernel_launch(void* const* d_in, const int* in_sizes, int n_in,
                              void* d_out, int out_size, void* d_ws, size_t ws_size,
                              hipStream_t stream)
{
  const float* f     = (const float*)d_in[0];
  const float* g     = (const float*)d_in[1];
  const float* We    = (const float*)d_in[2];
  const float* Wc    = (const float*)d_in[3];
  const float* Wg    = (const float*)d_in[4];
  const float* beta  = (const float*)d_in[5];
  const float* gamma = (const float*)d_in[6];
  const int* order   = (const int*)d_in[7];
  const int* parent  = (const int*)d_in[8];
  float* out = (float*)d_out;

  char* ws = (char*)d_ws;
  size_t off = 0;
  auto carve = [&](size_t bytes) -> void* {
    void* p = ws + off;
    off = (off + bytes + 255) & ~(size_t)255;
    return p;
  };
  float* emb   = (float*)carve((size_t)NB*NPIX*EMBW*4);    // 13.1 MB
  float* confA = (float*)carve((size_t)NB*NG*NPIX*4);      // 0.4 MB
  float* xspo  = (float*)carve((size_t)NB*NPIX*XW*4);      // 26.6 MB
  u16* wq    = (u16*)carve((size_t)NB*NG*NPIX*2);          // 0.2 MB
  u16* par16 = (u16*)carve((size_t)NB*NPIX*2);
  u16* cst16 = (u16*)carve((size_t)NB*6402*2);
  u16* inv16 = (u16*)carve((size_t)NB*NPIX*2);
  int* ls    = (int*)carve((size_t)NB*(NPIX+2)*4);
  int* nl    = (int*)carve((size_t)NB*4);

  const int sweep_lds = 128000 + 12800 + 12804;            // 153604
  const int tile_lds  = XW*TPITCH*4;                       // 67600
  hipFuncSetAttribute((const void*)sweep_kernel,
                      hipFuncAttributeMaxDynamicSharedMemorySize, sweep_lds);
  hipFuncSetAttribute((const void*)xbuild_kernel,
                      hipFuncAttributeMaxDynamicSharedMemorySize, tile_lds);
  hipFuncSetAttribute((const void*)epilogue_kernel,
                      hipFuncAttributeMaxDynamicSharedMemorySize, tile_lds);

  hipLaunchKernelGGL(prep_kernel,     dim3(NB),          dim3(256), 0, stream,
                     order, parent, par16, cst16, ls, nl, inv16);
  hipLaunchKernelGGL(gemm_kernel,     dim3(NPIX/TP, NB), dim3(512), 0, stream,
                     f, g, We, Wc, Wg, emb, confA);
  hipLaunchKernelGGL(wdist_kernel,    dim3(NB*100),      dim3(256), 0, stream,
                     emb, order, parent, beta, wq);
  hipLaunchKernelGGL(xbuild_kernel,   dim3(NB*100),      dim3(256), tile_lds, stream,
                     f, confA, inv16, xspo);
  hipLaunchKernelGGL(sweep_kernel,    dim3(NB*NG*13),    dim3(64),  sweep_lds, stream,
                     xspo, wq, par16, cst16, ls, nl);
  hipLaunchKernelGGL(epilogue_kernel, dim3(NB*100),      dim3(256), tile_lds, stream,
                     xspo, inv16, f, gamma, out);
}